// Round 12
// baseline (143.609 us; speedup 1.0000x reference)
//
#include <hip/hip_runtime.h>
#include <math.h>

typedef unsigned short ushortT;
typedef unsigned int uintT;
typedef __attribute__((ext_vector_type(8))) short short8;
typedef __attribute__((ext_vector_type(16))) float f32x16;
#define MFMA32(a, b, c) __builtin_amdgcn_mfma_f32_32x32x16_bf16((a), (b), (c), 0, 0, 0)

// MFMA 32x32x16 layouts (gfx950, HW-verified m74/m101/m120):
//  A-frag: lane reads A[m = lane&31][k = (lane>>5)*8 + j], j=0..7
//  B-frag: lane reads B[k = (lane>>5)*8 + j][n = lane&31]
//  C/D:    col = lane&31, row = (reg&3) + 8*(reg>>2) + 4*(lane>>5)
// Fragment-linear layout (R20/R21): element (m|n, k) lives at
//  [tile=(mn)>>5][ks=k>>4][lane=(mn&31)+32*((k>>3)&1)][j=k&7] -- one frag =
//  one coalesced 1KB wave load.

#define LOG2E 1.4426950408889634f

static __device__ __forceinline__ ushortT f2b(float f) {
    union { float f; uintT u; } v; v.f = f;
    uintT u = v.u;
    u += 0x7fffu + ((u >> 16) & 1u);     // round-to-nearest-even
    return (ushortT)(u >> 16);
}
static __device__ __forceinline__ uintT pack2(float a, float b) {
    return (uintT)f2b(a) | ((uintT)f2b(b) << 16);
}
// truncating bf16 pack of two fp32 in ONE v_perm_b32 (low16=a, high16=b)
static __device__ __forceinline__ uintT pack2t(float a, float b) {
    union { float f; uintT u; } x0, x1; x0.f = a; x1.f = b;
    return __builtin_amdgcn_perm(x1.u, x0.u, 0x07060302u);
}
static __device__ __forceinline__ float blo(uintT u) {
    union { uintT u; float f; } v; v.u = u << 16; return v.f;
}
static __device__ __forceinline__ float bhi(uintT u) {
    union { uintT u; float f; } v; v.u = u & 0xffff0000u; return v.f;
}
static __device__ __forceinline__ f32x16 zero16() {
    f32x16 z;
    #pragma unroll
    for (int i = 0; i < 16; ++i) z[i] = 0.f;
    return z;
}

#define NQB 16
#define NKB 32

// ---------------------------------------------------------------------------
// Fused prep (R21): x fp32 -> xbf FRAGMENT-LINEAR bf16 (blocks 0..2047);
// Wqkv transpose -> wbf fragment-linear (2048..2815); Wproj transpose ->
// wpt [n][k] linear (2816..3071, proj path unchanged).
// ---------------------------------------------------------------------------
__global__ __launch_bounds__(256) void prep_kernel(
    const float* __restrict__ x, ushortT* __restrict__ xbf,
    const float* __restrict__ Wq, ushortT* __restrict__ wbf,
    const float* __restrict__ Wp, ushortT* __restrict__ Wpt) {
    const int bid = blockIdx.x, t = threadIdx.x;
    __shared__ float tile[32][33];
    if (bid < 2048) {
        const int i = (bid * 256 + t) * 4;
        const int row = i >> 9, k = i & 511;
        float4 v = *(const float4*)(x + i);
        uint2 o; o.x = pack2(v.x, v.y); o.y = pack2(v.z, v.w);
        const int off = (((row >> 5) * 32 + (k >> 4)) << 9)
                      + (((row & 31) + 32 * ((k >> 3) & 1)) << 3) + (k & 7);
        *(uint2*)(xbf + off) = o;
        return;
    }
    const float* W; int C, c0, r0; bool isQkv;
    if (bid < 2816) {
        const int b = bid - 2048;
        W = Wq; C = 1536; isQkv = true;
        c0 = (b % 48) * 32; r0 = (b / 48) * 32;
    } else {
        const int b = bid - 2816;
        W = Wp; C = 512; isQkv = false;
        c0 = (b & 15) * 32; r0 = (b >> 4) * 32;
    }
    const int tx = t & 31, ty = t >> 5;
    #pragma unroll
    for (int i = 0; i < 4; ++i)
        tile[ty + 8 * i][tx] = W[(size_t)(r0 + ty + 8 * i) * C + c0 + tx];
    __syncthreads();
    #pragma unroll
    for (int i = 0; i < 4; ++i) {
        const int rr = ty + 8 * i;
        const ushortT val = f2b(tile[tx][rr]);
        const int n = c0 + rr, k = r0 + tx;
        if (isQkv) {
            const int off = (((n >> 5) * 32 + (k >> 4)) << 9)
                          + (((n & 31) + 32 * ((k >> 3) & 1)) << 3) + (k & 7);
            wbf[off] = val;
        } else {
            Wpt[(size_t)n * 512 + k] = val;
        }
    }
}

// ---------------------------------------------------------------------------
// QKV GEMM (bf16 MFMA). R21 barrier-free frag-streaming (verified: qkv
// dropped below fill noise). Epilogue: bias, qb/kfrag/vfrag scatter, means,
// fused cosine.
// ---------------------------------------------------------------------------
__global__ __launch_bounds__(256) void qkv_gemm_kernel(
    const ushortT* __restrict__ xbf, const ushortT* __restrict__ wbf,
    const float* __restrict__ bias,
    ushortT* __restrict__ qb, ushortT* __restrict__ kfrag, ushortT* __restrict__ vfrag,
    float* __restrict__ qm, float* __restrict__ km,
    float* __restrict__ qs, float* __restrict__ ks) {
    __shared__ float sumbuf[4][64];
    __shared__ float meanS[2][64];
    __shared__ float wminS[4];
    const int t = threadIdx.x;
    const int l = t & 63, w = t >> 6;
    const int lm = l & 31, lh = l >> 5;
    const int rowbase = blockIdx.y * 128;
    const int colbase = blockIdx.x * 64;

    const int rtile = blockIdx.y * 4 + w;
    const ushortT* Ab = xbf + ((size_t)rtile << 14);
    const ushortT* B0 = wbf + ((size_t)(blockIdx.x * 2) << 14);
    const ushortT* B1 = B0 + (1 << 14);

    f32x16 acc[2];
    acc[0] = zero16(); acc[1] = zero16();

    #pragma unroll 4
    for (int ks2 = 0; ks2 < 32; ++ks2) {
        short8 af = *(const short8*)(Ab + (ks2 << 9) + l * 8);
        short8 b0 = *(const short8*)(B0 + (ks2 << 9) + l * 8);
        short8 b1 = *(const short8*)(B1 + (ks2 << 9) + l * 8);
        acc[0] = MFMA32(af, b0, acc[0]);
        acc[1] = MFMA32(af, b1, acc[1]);
    }

    // epilogue: 64-col tile = exactly one (which, head)
    const int which = blockIdx.x >> 3;            // 0=q 1=k 2=v
    const int h = blockIdx.x & 7;
    const int by = blockIdx.y;
    const int b = by >> 4;
    const size_t hb = (size_t)(b * 8 + h);
    float bias2[2];
    #pragma unroll
    for (int nt = 0; nt < 2; ++nt) bias2[nt] = bias[colbase + 32 * nt + lm];
    float msum[2] = {0.f, 0.f};
    #pragma unroll
    for (int nt = 0; nt < 2; ++nt) {
        const int dd = 32 * nt + lm;
        #pragma unroll
        for (int rg = 0; rg < 16; ++rg) {
            const int row_local = 32 * w + (rg & 3) + 8 * (rg >> 2) + 4 * lh;
            const int ll = (rowbase + row_local) & 2047;
            float val = acc[nt][rg] + bias2[nt];
            if (which == 0) {
                val *= 0.125f;
                msum[nt] += val;
                qb[(hb * 2048 + ll) * 64 + dd] = f2b(val * LOG2E);
            } else if (which == 1) {
                msum[nt] += val;
                const int koff = (((ll >> 6) * 8 + ((ll >> 5) & 1) * 4 + (dd >> 4)) << 9)
                               + (((ll & 31) + 32 * ((dd >> 3) & 1)) << 3) + (dd & 7);
                kfrag[hb * 131072 + koff] = f2b(val);
            } else {
                const int voff = (((ll >> 6) * 8 + (dd >> 5) * 4 + ((ll >> 4) & 3)) << 9)
                               + (((dd & 31) + 32 * ((ll >> 3) & 1)) << 3) + (ll & 7);
                vfrag[hb * 131072 + voff] = f2b(val);
            }
            acc[nt][rg] = val;   // keep for fused cosine
        }
    }
    if (which == 2) return;
    #pragma unroll
    for (int nt = 0; nt < 2; ++nt) {
        float s = msum[nt] + __shfl_xor(msum[nt], 32);   // full 32-row col sum
        if (l < 32) sumbuf[w][32 * nt + lm] = s;
    }
    __syncthreads();
    // block means -> global + LDS (for cosine)
    if (which == 0) {
        if (t < 64) {
            const int qbi = by & 15;
            const float m =
                (sumbuf[0][t] + sumbuf[1][t] + sumbuf[2][t] + sumbuf[3][t]) * (1.0f / 128.0f);
            qm[(hb * 16 + qbi) * 64 + t] = m;
            meanS[0][t] = m;
        }
    } else {
        if (t < 128) {
            const int d = t & 63, pair = t >> 6;      // pair 0: waves 0-1, 1: waves 2-3
            const int kbi = 2 * (by & 15) + pair;
            const float m =
                (sumbuf[2 * pair][d] + sumbuf[2 * pair + 1][d]) * (1.0f / 64.0f);
            km[(hb * 32 + kbi) * 64 + d] = m;
            meanS[pair][d] = m;
        }
    }
    __syncthreads();
    // fused min-cosine-to-mean: thread holds cols {lm, 32+lm} of 16 rows
    {
        const int mrow = (which == 0) ? 0 : (w >> 1);
        const float mv0 = meanS[mrow][lm], mv1 = meanS[mrow][32 + lm];
        float mn2 = mv0 * mv0 + mv1 * mv1;
        #pragma unroll
        for (int off = 1; off < 32; off <<= 1) mn2 += __shfl_xor(mn2, off);
        const float mnorm = sqrtf(mn2);
        float cmin = 1e30f;
        #pragma unroll
        for (int rg = 0; rg < 16; ++rg) {
            float dp = acc[0][rg] * mv0 + acc[1][rg] * mv1;
            float nn = acc[0][rg] * acc[0][rg] + acc[1][rg] * acc[1][rg];
            #pragma unroll
            for (int off = 1; off < 32; off <<= 1) {
                dp += __shfl_xor(dp, off);
                nn += __shfl_xor(nn, off);
            }
            const float cosv = dp / ((sqrtf(nn) + 1e-6f) * (mnorm + 1e-6f));
            cmin = fminf(cmin, cosv);
        }
        cmin = fminf(cmin, __shfl_xor(cmin, 32));
        if (l == 0) wminS[w] = cmin;
    }
    __syncthreads();
    if (t == 0) {
        if (which == 0) {
            qs[hb * 16 + (by & 15)] =
                fminf(fminf(wminS[0], wminS[1]), fminf(wminS[2], wminS[3]));
        } else {
            ks[hb * 32 + 2 * (by & 15)]     = fminf(wminS[0], wminS[1]);
            ks[hb * 32 + 2 * (by & 15) + 1] = fminf(wminS[2], wminS[3]);
        }
    }
}

// ---------------------------------------------------------------------------
// Flash attention, bf16 MFMA, S^T form, exp2 softmax, inline mask (R14),
// barrier-free frag-streaming (R20). ROUND-22: OCCUPANCY DOUBLING -- R20
// counters: attn 45.7us, Occ 16% (1 block/CU = 2 waves/SIMD), MfmaUtil 13%,
// HBM 3% -> still latency-bound with nothing co-resident. Split each q-tile:
// grid (16 bh, 32 q64), block = 64 q-rows, wave = 32-q column tile (qf[4],
// oacc[2], single qh) -> VGPR ~110-120, LDS ~25KB -> 2 blocks/CU, 3-4
// waves/SIMD. Same dataflow otherwise; mask row = q64>>1 (computed by both
// half-blocks, cheap). launch_bounds cap-only (R4/R5 lesson).
// ---------------------------------------------------------------------------
__global__ __launch_bounds__(512, 2) void attn_kernel(
    const ushortT* __restrict__ qb, const ushortT* __restrict__ kfrag,
    const ushortT* __restrict__ vfrag,
    const float* __restrict__ qm, const float* __restrict__ km,
    const float* __restrict__ qs, const float* __restrict__ ks,
    ushortT* __restrict__ ob) {
    __shared__ __align__(16) uint4 ox[6 * 4 * 64];   // 24 KB bf16-packed partials
    __shared__ float lx[6 * 32];                     // 0.75 KB partial l
    __shared__ int klist[33];
    __shared__ float qmS[64];
    __shared__ float pnS[32];

    const int t = threadIdx.x;
    const int l = t & 63, w = t >> 6;
    const int lm = l & 31, lh = l >> 5;
    const int qc = w >> 2, kq = w & 3;        // q 32-group, klist stripe
    const int bh = blockIdx.x, q64 = blockIdx.y;   // q64: 64-row tile index 0..31
    const int qt = q64 >> 1;                       // mask row 0..15

    if (t < 64) qmS[t] = qm[((size_t)bh * 16 + qt) * 64 + t];

    // Q B-frags straight from global: wave qc owns q rows [q64*64+32qc, +32)
    const ushortT* qg = qb + ((size_t)bh * 2048 + q64 * 64) * 64;
    short8 qf[4];
    #pragma unroll
    for (int ksd = 0; ksd < 4; ++ksd)
        qf[ksd] = *(const short8*)(qg + (32 * qc + lm) * 64 + 16 * ksd + 8 * lh);
    __syncthreads();   // qmS visible

    // inline mask row (wave 0, lanes < 32): pooled softmax + CDF keep
    if (w == 0 && l < 32) {
        const float* kmr = km + ((size_t)bh * 32 + l) * 64;
        float dot = 0.f;
        #pragma unroll
        for (int d = 0; d < 64; ++d) dot += qmS[d] * kmr[d];
        float mx = dot;
        #pragma unroll
        for (int off = 1; off < 32; off <<= 1) mx = fmaxf(mx, __shfl_xor(mx, off));
        const float e = expf(dot - mx);
        float sum = e;
        #pragma unroll
        for (int off = 1; off < 32; off <<= 1) sum += __shfl_xor(sum, off);
        const float pn = e * (1.0f / sum);
        pnS[l] = pn;
        float before = 0.f;
        #pragma unroll
        for (int j = 0; j < 32; ++j) {
            const float pj = pnS[j];
            if (pj > pn || (pj == pn && j < l)) before += pj;
        }
        const bool qfb = !(qs[bh * 16 + qt] > 0.6f);
        const bool kfb = !(ks[bh * 32 + l] > 0.6f);
        const bool keep = (before < 0.98f) || qfb || kfb;
        unsigned long long bal = __ballot(keep);
        if (keep) {
            const int rank = __popcll(bal & ((1ULL << l) - 1ULL));
            klist[rank] = l;
        }
        if (l == 0) klist[32] = __popcll(bal);
    }
    __syncthreads();   // klist visible

    const int cnt = klist[32];
    const ushortT* kfb = kfrag + (size_t)bh * 131072;
    const ushortT* vfb = vfrag + (size_t)bh * 131072;

    f32x16 oacc[2];
    oacc[0] = zero16(); oacc[1] = zero16();
    float l_i = 0.f;

    for (int j = kq; j < cnt; j += 4) {
        const int kb = klist[j];
        const ushortT* kbase = kfb + kb * 4096;
        const ushortT* vbase = vfb + kb * 4096;
        #pragma unroll
        for (int kh = 0; kh < 2; ++kh) {
            // S^T = K * Q^T  (S already in log2e units), 32 keys this half
            f32x16 sacc = zero16();
            #pragma unroll
            for (int ksd = 0; ksd < 4; ++ksd) {
                short8 kf = *(const short8*)(kbase + ((kh * 4 + ksd) << 9) + l * 8);
                sacc = MFMA32(kf, qf[ksd], sacc);
            }
            // p = exp2(s)
            uintT uu[4][2];   // [rb][pair]
            float psum0 = 0.f, psum1 = 0.f;
            #pragma unroll
            for (int rp = 0; rp < 8; ++rp) {
                const float e0 = __builtin_amdgcn_exp2f(sacc[2 * rp]);
                const float e1 = __builtin_amdgcn_exp2f(sacc[2 * rp + 1]);
                psum0 += e0; psum1 += e1;
                uu[rp >> 1][rp & 1] = pack2t(e0, e1);
            }
            float psum = psum0 + psum1;
            psum += __shfl_xor(psum, 32);
            l_i += psum;
            // O^T += V^T * P^T ; P^T B-frag via lane pair-exchange
            #pragma unroll
            for (int ksk = 0; ksk < 2; ++ksk) {
                const int ksl = 2 * kh + ksk;
                short8 vf0 = *(const short8*)(vbase + (ksl << 9) + l * 8);
                short8 vf1 = *(const short8*)(vbase + ((4 + ksl) << 9) + l * 8);
                const uintT kA = lh ? uu[2 * ksk + 1][0] : uu[2 * ksk][0];
                const uintT kB = lh ? uu[2 * ksk + 1][1] : uu[2 * ksk][1];
                const uintT sA = lh ? uu[2 * ksk][0] : uu[2 * ksk + 1][0];
                const uintT sB = lh ? uu[2 * ksk][1] : uu[2 * ksk + 1][1];
                const uintT rA = (uintT)__shfl_xor((int)sA, 32);
                const uintT rB = (uintT)__shfl_xor((int)sB, 32);
                union { uintT u[4]; short8 v; } cv;
                if (lh == 0) { cv.u[0] = kA; cv.u[1] = kB; cv.u[2] = rA; cv.u[3] = rB; }
                else         { cv.u[0] = rA; cv.u[1] = rB; cv.u[2] = kA; cv.u[3] = kB; }
                oacc[0] = MFMA32(vf0, cv.v, oacc[0]);
                oacc[1] = MFMA32(vf1, cv.v, oacc[1]);
            }
        }
    }

    // ---- cross-kq reduction in LDS ----
    if (kq != 0) {
        const int wslot = qc * 3 + (kq - 1);
        #pragma unroll
        for (int dt = 0; dt < 2; ++dt)
            #pragma unroll
            for (int g2 = 0; g2 < 2; ++g2) {
                uint4 u;
                u.x = pack2(oacc[dt][8 * g2 + 0], oacc[dt][8 * g2 + 1]);
                u.y = pack2(oacc[dt][8 * g2 + 2], oacc[dt][8 * g2 + 3]);
                u.z = pack2(oacc[dt][8 * g2 + 4], oacc[dt][8 * g2 + 5]);
                u.w = pack2(oacc[dt][8 * g2 + 6], oacc[dt][8 * g2 + 7]);
                ox[(wslot * 4 + (dt * 2 + g2)) * 64 + l] = u;
            }
        if (lh == 0) lx[wslot * 32 + lm] = l_i;
    }
    __syncthreads();
    if (kq == 0) {
        float lt = l_i;
        #pragma unroll
        for (int p = 0; p < 3; ++p) {
            const int ws2 = qc * 3 + p;
            lt += lx[ws2 * 32 + lm];
            #pragma unroll
            for (int dt = 0; dt < 2; ++dt)
                #pragma unroll
                for (int g2 = 0; g2 < 2; ++g2) {
                    uint4 u = ox[(ws2 * 4 + (dt * 2 + g2)) * 64 + l];
                    oacc[dt][8 * g2 + 0] += blo(u.x);
                    oacc[dt][8 * g2 + 1] += bhi(u.x);
                    oacc[dt][8 * g2 + 2] += blo(u.y);
                    oacc[dt][8 * g2 + 3] += bhi(u.y);
                    oacc[dt][8 * g2 + 4] += blo(u.z);
                    oacc[dt][8 * g2 + 5] += bhi(u.z);
                    oacc[dt][8 * g2 + 6] += blo(u.w);
                    oacc[dt][8 * g2 + 7] += bhi(u.w);
                }
        }
        const float inv = 1.0f / lt;
        const int token = q64 * 64 + qc * 32 + lm;
        ushortT* orow = ob + ((size_t)bh * 2048 + token) * 64;
        #pragma unroll
        for (int dt = 0; dt < 2; ++dt)
            #pragma unroll
            for (int rp = 0; rp < 8; ++rp) {
                const int d0 = 32 * dt + 8 * (rp >> 1) + 4 * lh + 2 * (rp & 1);
                *(uintT*)(orow + d0) =
                    pack2(oacc[dt][2 * rp] * inv, oacc[dt][2 * rp + 1] * inv);
            }
    }
}

// ---------------------------------------------------------------------------
// Proj GEMM: 64x64 tiles, grid (8,64) = 512 blocks = 2 waves/SIMD.
// ob (gathered [4096,512] bf16) @ Wprojt^T + bias -> out fp32.
// ---------------------------------------------------------------------------
__global__ __launch_bounds__(256) void proj_gemm_kernel(
    const ushortT* __restrict__ ob, const ushortT* __restrict__ wpt,
    const float* __restrict__ bias, float* __restrict__ out) {
    __shared__ __align__(16) ushortT As[2][64 * 40];
    __shared__ __align__(16) ushortT Bs[2][64 * 40];
    const int t = threadIdx.x;
    const int l = t & 63, w = t >> 6;
    const int lm = l & 31, lh = l >> 5;
    const int rh = w & 1, ch = w >> 1;            // wave -> 32-row half, 32-col half
    const int rowbase = blockIdx.y * 64;
    const int colbase = blockIdx.x * 64;

    f32x16 acc = zero16();

    const int r = t >> 2, q4 = t & 3;             // row 0..63, k-quarter (8 elems)
    const int token = rowbase + r;
    const int b2 = token >> 11, lt = token & 2047;
    const int so = r * 40 + q4 * 8;
    const ushortT* obbase = ob + ((size_t)(b2 * 8) * 2048 + lt) * 64 + q4 * 8;
    const ushortT* Bg = wpt + (size_t)(colbase + r) * 512 + q4 * 8;

    uint4 a0, b0;
    a0 = *(const uint4*)(obbase);
    b0 = *(const uint4*)(Bg);
    *(uint4*)(&As[0][so]) = a0;
    *(uint4*)(&Bs[0][so]) = b0;

    for (int k0 = 0; k0 < 512; k0 += 32) {
        const int cur = (k0 >> 5) & 1;
        __syncthreads();
        if (k0 < 480) {
            const int kn = k0 + 32;
            const ushortT* Ag = obbase + (size_t)(kn >> 6) * 131072 + (kn & 63);
            a0 = *(const uint4*)(Ag);
            b0 = *(const uint4*)(Bg + kn);
        }
        #pragma unroll
        for (int ks2 = 0; ks2 < 2; ++ks2) {
            const int ko = 16 * ks2 + 8 * lh;
            short8 af = *(const short8*)(&As[cur][(32 * rh + lm) * 40 + ko]);
            short8 bf = *(const short8*)(&Bs[cur][(32 * ch + lm) * 40 + ko]);
            acc = MFMA32(af, bf, acc);
        }
        if (k0 < 480) {
            const int nxt = cur ^ 1;
            *(uint4*)(&As[nxt][so]) = a0;
            *(uint4*)(&Bs[nxt][so]) = b0;
        }
    }
    const int c = colbase + 32 * ch + lm;
    const float bb = bias[c];
    #pragma unroll
    for (int rg = 0; rg < 16; ++rg) {
        const int row_local = 32 * rh + (rg & 3) + 8 * (rg >> 2) + 4 * lh;
        out[(size_t)(rowbase + row_local) * 512 + c] = acc[rg] + bb;
    }
}

// ---------------------------------------------------------------------------
extern "C" void kernel_launch(void* const* d_in, const int* in_sizes, int n_in,
                              void* d_out, int out_size, void* d_ws, size_t ws_size,
                              hipStream_t stream) {
    const float* x     = (const float*)d_in[0];
    const float* Wqkv  = (const float*)d_in[1];
    const float* bqkv  = (const float*)d_in[2];
    const float* Wproj = (const float*)d_in[3];
    const float* bproj = (const float*)d_in[4];
    float* out = (float*)d_out;

    char* w = (char*)d_ws;
    ushortT* xbf    = (ushortT*)(w);                    // 4 MB (fragment-linear x)
    ushortT* wbf    = (ushortT*)(w + 4194304);          // 1.5 MB (fragment-linear Wqkv^T)
    ushortT* wprojt = (ushortT*)(w + 5767168);          // 0.5 MB
    ushortT* qb     = (ushortT*)(w + 6291456);          // 4 MB (scaled 0.125*log2e)
    ushortT* kfrag  = (ushortT*)(w + 10485760);         // 4 MB (fragment-linear K)
    ushortT* vfrag  = (ushortT*)(w + 14680064);         // 4 MB (fragment-linear V)
    ushortT* ob     = (ushortT*)(w + 18874368);         // 4 MB (final attention output)
    float*   qm     = (float*)(w + 23068672);           // 64 KB
    float*   km     = (float*)(w + 23134208);           // 128 KB
    float*   qs     = (float*)(w + 36406272);           // 1 KB
    float*   ks     = (float*)(w + 36407296);           // 2 KB

    prep_kernel<<<3072, 256, 0, stream>>>(x, xbf, Wqkv, wbf, Wproj, wprojt);
    qkv_gemm_kernel<<<dim3(24, 32), 256, 0, stream>>>(xbf, wbf, bqkv, qb, kfrag, vfrag,
                                                      qm, km, qs, ks);
    attn_kernel<<<dim3(16, 32), 512, 0, stream>>>(qb, kfrag, vfrag, qm, km, qs, ks, ob);
    proj_gemm_kernel<<<dim3(8, 64), 256, 0, stream>>>(ob, wprojt, bproj, out);
}

// Round 13
// 128.010 us; speedup vs baseline: 1.1219x; 1.1219x over previous
//
#include <hip/hip_runtime.h>
#include <math.h>

typedef unsigned short ushortT;
typedef unsigned int uintT;
typedef __attribute__((ext_vector_type(8))) short short8;
typedef __attribute__((ext_vector_type(16))) float f32x16;
#define MFMA32(a, b, c) __builtin_amdgcn_mfma_f32_32x32x16_bf16((a), (b), (c), 0, 0, 0)

// MFMA 32x32x16 layouts (gfx950, HW-verified m74/m101/m120):
//  A-frag: lane reads A[m = lane&31][k = (lane>>5)*8 + j], j=0..7
//  B-frag: lane reads B[k = (lane>>5)*8 + j][n = lane&31]
//  C/D:    col = lane&31, row = (reg&3) + 8*(reg>>2) + 4*(lane>>5)
// Fragment-linear layout (R20/R21): element (m|n, k) lives at
//  [tile=(mn)>>5][ks=k>>4][lane=(mn&31)+32*((k>>3)&1)][j=k&7] -- one frag =
//  one coalesced 1KB wave load.

#define LOG2E 1.4426950408889634f

static __device__ __forceinline__ ushortT f2b(float f) {
    union { float f; uintT u; } v; v.f = f;
    uintT u = v.u;
    u += 0x7fffu + ((u >> 16) & 1u);     // round-to-nearest-even
    return (ushortT)(u >> 16);
}
static __device__ __forceinline__ uintT pack2(float a, float b) {
    return (uintT)f2b(a) | ((uintT)f2b(b) << 16);
}
// truncating bf16 pack of two fp32 in ONE v_perm_b32 (low16=a, high16=b)
static __device__ __forceinline__ uintT pack2t(float a, float b) {
    union { float f; uintT u; } x0, x1; x0.f = a; x1.f = b;
    return __builtin_amdgcn_perm(x1.u, x0.u, 0x07060302u);
}
static __device__ __forceinline__ float blo(uintT u) {
    union { uintT u; float f; } v; v.u = u << 16; return v.f;
}
static __device__ __forceinline__ float bhi(uintT u) {
    union { uintT u; float f; } v; v.u = u & 0xffff0000u; return v.f;
}
static __device__ __forceinline__ f32x16 zero16() {
    f32x16 z;
    #pragma unroll
    for (int i = 0; i < 16; ++i) z[i] = 0.f;
    return z;
}

#define NQB 16
#define NKB 32

// ---------------------------------------------------------------------------
// Fused prep (R21): x fp32 -> xbf FRAGMENT-LINEAR bf16 (blocks 0..2047);
// Wqkv transpose -> wbf fragment-linear (2048..2815); Wproj transpose ->
// wpt [n][k] linear (2816..3071, proj path unchanged).
// ---------------------------------------------------------------------------
__global__ __launch_bounds__(256) void prep_kernel(
    const float* __restrict__ x, ushortT* __restrict__ xbf,
    const float* __restrict__ Wq, ushortT* __restrict__ wbf,
    const float* __restrict__ Wp, ushortT* __restrict__ Wpt) {
    const int bid = blockIdx.x, t = threadIdx.x;
    __shared__ float tile[32][33];
    if (bid < 2048) {
        const int i = (bid * 256 + t) * 4;
        const int row = i >> 9, k = i & 511;
        float4 v = *(const float4*)(x + i);
        uint2 o; o.x = pack2(v.x, v.y); o.y = pack2(v.z, v.w);
        const int off = (((row >> 5) * 32 + (k >> 4)) << 9)
                      + (((row & 31) + 32 * ((k >> 3) & 1)) << 3) + (k & 7);
        *(uint2*)(xbf + off) = o;
        return;
    }
    const float* W; int C, c0, r0; bool isQkv;
    if (bid < 2816) {
        const int b = bid - 2048;
        W = Wq; C = 1536; isQkv = true;
        c0 = (b % 48) * 32; r0 = (b / 48) * 32;
    } else {
        const int b = bid - 2816;
        W = Wp; C = 512; isQkv = false;
        c0 = (b & 15) * 32; r0 = (b >> 4) * 32;
    }
    const int tx = t & 31, ty = t >> 5;
    #pragma unroll
    for (int i = 0; i < 4; ++i)
        tile[ty + 8 * i][tx] = W[(size_t)(r0 + ty + 8 * i) * C + c0 + tx];
    __syncthreads();
    #pragma unroll
    for (int i = 0; i < 4; ++i) {
        const int rr = ty + 8 * i;
        const ushortT val = f2b(tile[tx][rr]);
        const int n = c0 + rr, k = r0 + tx;
        if (isQkv) {
            const int off = (((n >> 5) * 32 + (k >> 4)) << 9)
                          + (((n & 31) + 32 * ((k >> 3) & 1)) << 3) + (k & 7);
            wbf[off] = val;
        } else {
            Wpt[(size_t)n * 512 + k] = val;
        }
    }
}

// ---------------------------------------------------------------------------
// QKV GEMM (bf16 MFMA). R21 barrier-free frag-streaming (verified: qkv
// dropped below fill noise). Epilogue: bias, qb/kfrag/vfrag scatter, means,
// fused cosine.
// ---------------------------------------------------------------------------
__global__ __launch_bounds__(256) void qkv_gemm_kernel(
    const ushortT* __restrict__ xbf, const ushortT* __restrict__ wbf,
    const float* __restrict__ bias,
    ushortT* __restrict__ qb, ushortT* __restrict__ kfrag, ushortT* __restrict__ vfrag,
    float* __restrict__ qm, float* __restrict__ km,
    float* __restrict__ qs, float* __restrict__ ks) {
    __shared__ float sumbuf[4][64];
    __shared__ float meanS[2][64];
    __shared__ float wminS[4];
    const int t = threadIdx.x;
    const int l = t & 63, w = t >> 6;
    const int lm = l & 31, lh = l >> 5;
    const int rowbase = blockIdx.y * 128;
    const int colbase = blockIdx.x * 64;

    const int rtile = blockIdx.y * 4 + w;
    const ushortT* Ab = xbf + ((size_t)rtile << 14);
    const ushortT* B0 = wbf + ((size_t)(blockIdx.x * 2) << 14);
    const ushortT* B1 = B0 + (1 << 14);

    f32x16 acc[2];
    acc[0] = zero16(); acc[1] = zero16();

    #pragma unroll 4
    for (int ks2 = 0; ks2 < 32; ++ks2) {
        short8 af = *(const short8*)(Ab + (ks2 << 9) + l * 8);
        short8 b0 = *(const short8*)(B0 + (ks2 << 9) + l * 8);
        short8 b1 = *(const short8*)(B1 + (ks2 << 9) + l * 8);
        acc[0] = MFMA32(af, b0, acc[0]);
        acc[1] = MFMA32(af, b1, acc[1]);
    }

    // epilogue: 64-col tile = exactly one (which, head)
    const int which = blockIdx.x >> 3;            // 0=q 1=k 2=v
    const int h = blockIdx.x & 7;
    const int by = blockIdx.y;
    const int b = by >> 4;
    const size_t hb = (size_t)(b * 8 + h);
    float bias2[2];
    #pragma unroll
    for (int nt = 0; nt < 2; ++nt) bias2[nt] = bias[colbase + 32 * nt + lm];
    float msum[2] = {0.f, 0.f};
    #pragma unroll
    for (int nt = 0; nt < 2; ++nt) {
        const int dd = 32 * nt + lm;
        #pragma unroll
        for (int rg = 0; rg < 16; ++rg) {
            const int row_local = 32 * w + (rg & 3) + 8 * (rg >> 2) + 4 * lh;
            const int ll = (rowbase + row_local) & 2047;
            float val = acc[nt][rg] + bias2[nt];
            if (which == 0) {
                val *= 0.125f;
                msum[nt] += val;
                qb[(hb * 2048 + ll) * 64 + dd] = f2b(val * LOG2E);
            } else if (which == 1) {
                msum[nt] += val;
                const int koff = (((ll >> 6) * 8 + ((ll >> 5) & 1) * 4 + (dd >> 4)) << 9)
                               + (((ll & 31) + 32 * ((dd >> 3) & 1)) << 3) + (dd & 7);
                kfrag[hb * 131072 + koff] = f2b(val);
            } else {
                const int voff = (((ll >> 6) * 8 + (dd >> 5) * 4 + ((ll >> 4) & 3)) << 9)
                               + (((dd & 31) + 32 * ((ll >> 3) & 1)) << 3) + (ll & 7);
                vfrag[hb * 131072 + voff] = f2b(val);
            }
            acc[nt][rg] = val;   // keep for fused cosine
        }
    }
    if (which == 2) return;
    #pragma unroll
    for (int nt = 0; nt < 2; ++nt) {
        float s = msum[nt] + __shfl_xor(msum[nt], 32);   // full 32-row col sum
        if (l < 32) sumbuf[w][32 * nt + lm] = s;
    }
    __syncthreads();
    // block means -> global + LDS (for cosine)
    if (which == 0) {
        if (t < 64) {
            const int qbi = by & 15;
            const float m =
                (sumbuf[0][t] + sumbuf[1][t] + sumbuf[2][t] + sumbuf[3][t]) * (1.0f / 128.0f);
            qm[(hb * 16 + qbi) * 64 + t] = m;
            meanS[0][t] = m;
        }
    } else {
        if (t < 128) {
            const int d = t & 63, pair = t >> 6;      // pair 0: waves 0-1, 1: waves 2-3
            const int kbi = 2 * (by & 15) + pair;
            const float m =
                (sumbuf[2 * pair][d] + sumbuf[2 * pair + 1][d]) * (1.0f / 64.0f);
            km[(hb * 32 + kbi) * 64 + d] = m;
            meanS[pair][d] = m;
        }
    }
    __syncthreads();
    // fused min-cosine-to-mean: thread holds cols {lm, 32+lm} of 16 rows
    {
        const int mrow = (which == 0) ? 0 : (w >> 1);
        const float mv0 = meanS[mrow][lm], mv1 = meanS[mrow][32 + lm];
        float mn2 = mv0 * mv0 + mv1 * mv1;
        #pragma unroll
        for (int off = 1; off < 32; off <<= 1) mn2 += __shfl_xor(mn2, off);
        const float mnorm = sqrtf(mn2);
        float cmin = 1e30f;
        #pragma unroll
        for (int rg = 0; rg < 16; ++rg) {
            float dp = acc[0][rg] * mv0 + acc[1][rg] * mv1;
            float nn = acc[0][rg] * acc[0][rg] + acc[1][rg] * acc[1][rg];
            #pragma unroll
            for (int off = 1; off < 32; off <<= 1) {
                dp += __shfl_xor(dp, off);
                nn += __shfl_xor(nn, off);
            }
            const float cosv = dp / ((sqrtf(nn) + 1e-6f) * (mnorm + 1e-6f));
            cmin = fminf(cmin, cosv);
        }
        cmin = fminf(cmin, __shfl_xor(cmin, 32));
        if (l == 0) wminS[w] = cmin;
    }
    __syncthreads();
    if (t == 0) {
        if (which == 0) {
            qs[hb * 16 + (by & 15)] =
                fminf(fminf(wminS[0], wminS[1]), fminf(wminS[2], wminS[3]));
        } else {
            ks[hb * 32 + 2 * (by & 15)]     = fminf(wminS[0], wminS[1]);
            ks[hb * 32 + 2 * (by & 15) + 1] = fminf(wminS[2], wminS[3]);
        }
    }
}

// ---------------------------------------------------------------------------
// Flash attention, bf16 MFMA, S^T form, exp2 softmax, inline mask (R14),
// barrier-free frag-streaming (R20). ROUND-23: EXPLICIT LOAD BATCHING --
// R22 proved occupancy is NOT the limiter (Occ 16->37%, dur unchanged);
// R22's VGPR=56 exposed the real one: the compiler holds only ~1-2 frag
// loads in flight, so each of the 16 L2 loads per K-block pays its full
// ~225cyc latency serially. Fix: load ALL 16 frags (8 K + 8 V) of the
// current K-block into named unrolled register arrays BEFORE any MFMA --
// one latency wait per block instead of 16; V latency hides under QK+exp.
// launch_bounds (512,1) lifts the 128-VGPR cap (expect ~230, no spill;
// flat body + static indices only -- R17/R20 lessons). Grid (16,16),
// 2-qh waves (R21's best-attn config). Epilogue unchanged.
// ---------------------------------------------------------------------------
__global__ __launch_bounds__(512, 1) void attn_kernel(
    const ushortT* __restrict__ qb, const ushortT* __restrict__ kfrag,
    const ushortT* __restrict__ vfrag,
    const float* __restrict__ qm, const float* __restrict__ km,
    const float* __restrict__ qs, const float* __restrict__ ks,
    ushortT* __restrict__ ob) {
    __shared__ __align__(16) uint4 ox[6 * 8 * 64];   // 48 KB bf16-packed partials
    __shared__ float lx[6 * 2 * 32];                 // 1.5 KB partial l
    __shared__ int klist[33];
    __shared__ float qmS[64];
    __shared__ float pnS[32];

    const int t = threadIdx.x;
    const int l = t & 63, w = t >> 6;
    const int lm = l & 31, lh = l >> 5;
    const int qc = w >> 2, kq = w & 3;        // q 64-group, klist stripe
    const int bh = blockIdx.x, qt = blockIdx.y;

    if (t < 64) qmS[t] = qm[((size_t)bh * 16 + qt) * 64 + t];

    // Q B-frags straight from global: wave qc owns q rows [64qc, 64qc+64)
    const ushortT* qg = qb + ((size_t)bh * 2048 + qt * 128) * 64;
    short8 qf[4][2];
    #pragma unroll
    for (int qh = 0; qh < 2; ++qh)
        #pragma unroll
        for (int ksd = 0; ksd < 4; ++ksd)
            qf[ksd][qh] = *(const short8*)(qg + (64 * qc + 32 * qh + lm) * 64 + 16 * ksd + 8 * lh);
    __syncthreads();   // qmS visible

    // inline mask row (wave 0, lanes < 32): pooled softmax + CDF keep
    if (w == 0 && l < 32) {
        const float* kmr = km + ((size_t)bh * 32 + l) * 64;
        float dot = 0.f;
        #pragma unroll
        for (int d = 0; d < 64; ++d) dot += qmS[d] * kmr[d];
        float mx = dot;
        #pragma unroll
        for (int off = 1; off < 32; off <<= 1) mx = fmaxf(mx, __shfl_xor(mx, off));
        const float e = expf(dot - mx);
        float sum = e;
        #pragma unroll
        for (int off = 1; off < 32; off <<= 1) sum += __shfl_xor(sum, off);
        const float pn = e * (1.0f / sum);
        pnS[l] = pn;
        float before = 0.f;
        #pragma unroll
        for (int j = 0; j < 32; ++j) {
            const float pj = pnS[j];
            if (pj > pn || (pj == pn && j < l)) before += pj;
        }
        const bool qfb = !(qs[bh * 16 + qt] > 0.6f);
        const bool kfb = !(ks[bh * 32 + l] > 0.6f);
        const bool keep = (before < 0.98f) || qfb || kfb;
        unsigned long long bal = __ballot(keep);
        if (keep) {
            const int rank = __popcll(bal & ((1ULL << l) - 1ULL));
            klist[rank] = l;
        }
        if (l == 0) klist[32] = __popcll(bal);
    }
    __syncthreads();   // klist visible

    const int cnt = klist[32];
    const ushortT* kfb = kfrag + (size_t)bh * 131072;
    const ushortT* vfb = vfrag + (size_t)bh * 131072;

    f32x16 oacc[2][2];
    oacc[0][0] = zero16(); oacc[1][0] = zero16();
    oacc[0][1] = zero16(); oacc[1][1] = zero16();
    float l_i[2] = {0.f, 0.f};

    for (int j = kq; j < cnt; j += 4) {
        const int kb = klist[j];
        const ushortT* kbase = kfb + kb * 4096;
        const ushortT* vbase = vfb + kb * 4096;
        // batch-load ALL 16 frags of this K-block (independent 1KB wave
        // loads issue back-to-back; one vmcnt wait instead of 16)
        short8 kf[8], vf[8];
        #pragma unroll
        for (int f = 0; f < 8; ++f)
            kf[f] = *(const short8*)(kbase + (f << 9) + l * 8);
        #pragma unroll
        for (int f = 0; f < 8; ++f)
            vf[f] = *(const short8*)(vbase + (f << 9) + l * 8);
        #pragma unroll
        for (int kh = 0; kh < 2; ++kh) {
            // S^T = K * Q^T  (S already in log2e units), 32 keys this half
            f32x16 sacc[2];
            sacc[0] = zero16(); sacc[1] = zero16();
            #pragma unroll
            for (int ksd = 0; ksd < 4; ++ksd) {
                sacc[0] = MFMA32(kf[kh * 4 + ksd], qf[ksd][0], sacc[0]);
                sacc[1] = MFMA32(kf[kh * 4 + ksd], qf[ksd][1], sacc[1]);
            }
            // p = exp2(s)
            uintT uu[2][4][2];   // [qh][rb][pair]
            #pragma unroll
            for (int qh = 0; qh < 2; ++qh) {
                float psum0 = 0.f, psum1 = 0.f;
                #pragma unroll
                for (int rp = 0; rp < 8; ++rp) {
                    const float e0 = __builtin_amdgcn_exp2f(sacc[qh][2 * rp]);
                    const float e1 = __builtin_amdgcn_exp2f(sacc[qh][2 * rp + 1]);
                    psum0 += e0; psum1 += e1;
                    uu[qh][rp >> 1][rp & 1] = pack2t(e0, e1);
                }
                float psum = psum0 + psum1;
                psum += __shfl_xor(psum, 32);
                l_i[qh] += psum;
            }
            // O^T += V^T * P^T ; P^T B-frag via lane pair-exchange
            #pragma unroll
            for (int ksk = 0; ksk < 2; ++ksk) {
                const int ksl = 2 * kh + ksk;
                #pragma unroll
                for (int qh = 0; qh < 2; ++qh) {
                    const uintT kA = lh ? uu[qh][2 * ksk + 1][0] : uu[qh][2 * ksk][0];
                    const uintT kB = lh ? uu[qh][2 * ksk + 1][1] : uu[qh][2 * ksk][1];
                    const uintT sA = lh ? uu[qh][2 * ksk][0] : uu[qh][2 * ksk + 1][0];
                    const uintT sB = lh ? uu[qh][2 * ksk][1] : uu[qh][2 * ksk + 1][1];
                    const uintT rA = (uintT)__shfl_xor((int)sA, 32);
                    const uintT rB = (uintT)__shfl_xor((int)sB, 32);
                    union { uintT u[4]; short8 v; } cv;
                    if (lh == 0) { cv.u[0] = kA; cv.u[1] = kB; cv.u[2] = rA; cv.u[3] = rB; }
                    else         { cv.u[0] = rA; cv.u[1] = rB; cv.u[2] = kA; cv.u[3] = kB; }
                    oacc[0][qh] = MFMA32(vf[ksl], cv.v, oacc[0][qh]);
                    oacc[1][qh] = MFMA32(vf[4 + ksl], cv.v, oacc[1][qh]);
                }
            }
        }
    }

    // ---- cross-kq reduction in LDS ----
    if (kq != 0) {
        const int wslot = qc * 3 + (kq - 1);
        #pragma unroll
        for (int dt = 0; dt < 2; ++dt)
            #pragma unroll
            for (int qh = 0; qh < 2; ++qh)
                #pragma unroll
                for (int g2 = 0; g2 < 2; ++g2) {
                    uint4 u;
                    u.x = pack2(oacc[dt][qh][8 * g2 + 0], oacc[dt][qh][8 * g2 + 1]);
                    u.y = pack2(oacc[dt][qh][8 * g2 + 2], oacc[dt][qh][8 * g2 + 3]);
                    u.z = pack2(oacc[dt][qh][8 * g2 + 4], oacc[dt][qh][8 * g2 + 5]);
                    u.w = pack2(oacc[dt][qh][8 * g2 + 6], oacc[dt][qh][8 * g2 + 7]);
                    ox[(wslot * 8 + (dt * 4 + qh * 2 + g2)) * 64 + l] = u;
                }
        if (lh == 0) {
            lx[(wslot * 2 + 0) * 32 + lm] = l_i[0];
            lx[(wslot * 2 + 1) * 32 + lm] = l_i[1];
        }
    }
    __syncthreads();
    if (kq == 0) {
        float lt[2] = {l_i[0], l_i[1]};
        #pragma unroll
        for (int p = 0; p < 3; ++p) {
            const int ws2 = qc * 3 + p;
            lt[0] += lx[(ws2 * 2 + 0) * 32 + lm];
            lt[1] += lx[(ws2 * 2 + 1) * 32 + lm];
            #pragma unroll
            for (int dt = 0; dt < 2; ++dt)
                #pragma unroll
                for (int qh = 0; qh < 2; ++qh)
                    #pragma unroll
                    for (int g2 = 0; g2 < 2; ++g2) {
                        uint4 u = ox[(ws2 * 8 + (dt * 4 + qh * 2 + g2)) * 64 + l];
                        oacc[dt][qh][8 * g2 + 0] += blo(u.x);
                        oacc[dt][qh][8 * g2 + 1] += bhi(u.x);
                        oacc[dt][qh][8 * g2 + 2] += blo(u.y);
                        oacc[dt][qh][8 * g2 + 3] += bhi(u.y);
                        oacc[dt][qh][8 * g2 + 4] += blo(u.z);
                        oacc[dt][qh][8 * g2 + 5] += bhi(u.z);
                        oacc[dt][qh][8 * g2 + 6] += blo(u.w);
                        oacc[dt][qh][8 * g2 + 7] += bhi(u.w);
                    }
        }
        #pragma unroll
        for (int qh = 0; qh < 2; ++qh) {
            const float inv = 1.0f / lt[qh];
            const int token = qt * 128 + qc * 64 + 32 * qh + lm;
            ushortT* orow = ob + ((size_t)bh * 2048 + token) * 64;
            #pragma unroll
            for (int dt = 0; dt < 2; ++dt)
                #pragma unroll
                for (int rp = 0; rp < 8; ++rp) {
                    const int d0 = 32 * dt + 8 * (rp >> 1) + 4 * lh + 2 * (rp & 1);
                    *(uintT*)(orow + d0) =
                        pack2(oacc[dt][qh][2 * rp] * inv, oacc[dt][qh][2 * rp + 1] * inv);
                }
        }
    }
}

// ---------------------------------------------------------------------------
// Proj GEMM: 64x64 tiles, grid (8,64) = 512 blocks = 2 waves/SIMD.
// ob (gathered [4096,512] bf16) @ Wprojt^T + bias -> out fp32.
// ---------------------------------------------------------------------------
__global__ __launch_bounds__(256) void proj_gemm_kernel(
    const ushortT* __restrict__ ob, const ushortT* __restrict__ wpt,
    const float* __restrict__ bias, float* __restrict__ out) {
    __shared__ __align__(16) ushortT As[2][64 * 40];
    __shared__ __align__(16) ushortT Bs[2][64 * 40];
    const int t = threadIdx.x;
    const int l = t & 63, w = t >> 6;
    const int lm = l & 31, lh = l >> 5;
    const int rh = w & 1, ch = w >> 1;            // wave -> 32-row half, 32-col half
    const int rowbase = blockIdx.y * 64;
    const int colbase = blockIdx.x * 64;

    f32x16 acc = zero16();

    const int r = t >> 2, q4 = t & 3;             // row 0..63, k-quarter (8 elems)
    const int token = rowbase + r;
    const int b2 = token >> 11, lt = token & 2047;
    const int so = r * 40 + q4 * 8;
    const ushortT* obbase = ob + ((size_t)(b2 * 8) * 2048 + lt) * 64 + q4 * 8;
    const ushortT* Bg = wpt + (size_t)(colbase + r) * 512 + q4 * 8;

    uint4 a0, b0;
    a0 = *(const uint4*)(obbase);
    b0 = *(const uint4*)(Bg);
    *(uint4*)(&As[0][so]) = a0;
    *(uint4*)(&Bs[0][so]) = b0;

    for (int k0 = 0; k0 < 512; k0 += 32) {
        const int cur = (k0 >> 5) & 1;
        __syncthreads();
        if (k0 < 480) {
            const int kn = k0 + 32;
            const ushortT* Ag = obbase + (size_t)(kn >> 6) * 131072 + (kn & 63);
            a0 = *(const uint4*)(Ag);
            b0 = *(const uint4*)(Bg + kn);
        }
        #pragma unroll
        for (int ks2 = 0; ks2 < 2; ++ks2) {
            const int ko = 16 * ks2 + 8 * lh;
            short8 af = *(const short8*)(&As[cur][(32 * rh + lm) * 40 + ko]);
            short8 bf = *(const short8*)(&Bs[cur][(32 * ch + lm) * 40 + ko]);
            acc = MFMA32(af, bf, acc);
        }
        if (k0 < 480) {
            const int nxt = cur ^ 1;
            *(uint4*)(&As[nxt][so]) = a0;
            *(uint4*)(&Bs[nxt][so]) = b0;
        }
    }
    const int c = colbase + 32 * ch + lm;
    const float bb = bias[c];
    #pragma unroll
    for (int rg = 0; rg < 16; ++rg) {
        const int row_local = 32 * rh + (rg & 3) + 8 * (rg >> 2) + 4 * lh;
        out[(size_t)(rowbase + row_local) * 512 + c] = acc[rg] + bb;
    }
}

// ---------------------------------------------------------------------------
extern "C" void kernel_launch(void* const* d_in, const int* in_sizes, int n_in,
                              void* d_out, int out_size, void* d_ws, size_t ws_size,
                              hipStream_t stream) {
    const float* x     = (const float*)d_in[0];
    const float* Wqkv  = (const float*)d_in[1];
    const float* bqkv  = (const float*)d_in[2];
    const float* Wproj = (const float*)d_in[3];
    const float* bproj = (const float*)d_in[4];
    float* out = (float*)d_out;

    char* w = (char*)d_ws;
    ushortT* xbf    = (ushortT*)(w);                    // 4 MB (fragment-linear x)
    ushortT* wbf    = (ushortT*)(w + 4194304);          // 1.5 MB (fragment-linear Wqkv^T)
    ushortT* wprojt = (ushortT*)(w + 5767168);          // 0.5 MB
    ushortT* qb     = (ushortT*)(w + 6291456);          // 4 MB (scaled 0.125*log2e)
    ushortT* kfrag  = (ushortT*)(w + 10485760);         // 4 MB (fragment-linear K)
    ushortT* vfrag  = (ushortT*)(w + 14680064);         // 4 MB (fragment-linear V)
    ushortT* ob     = (ushortT*)(w + 18874368);         // 4 MB (final attention output)
    float*   qm     = (float*)(w + 23068672);           // 64 KB
    float*   km     = (float*)(w + 23134208);           // 128 KB
    float*   qs     = (float*)(w + 36406272);           // 1 KB
    float*   ks     = (float*)(w + 36407296);           // 2 KB

    prep_kernel<<<3072, 256, 0, stream>>>(x, xbf, Wqkv, wbf, Wproj, wprojt);
    qkv_gemm_kernel<<<dim3(24, 32), 256, 0, stream>>>(xbf, wbf, bqkv, qb, kfrag, vfrag,
                                                      qm, km, qs, ks);
    attn_kernel<<<dim3(16, 16), 512, 0, stream>>>(qb, kfrag, vfrag, qm, km, qs, ks, ob);
    proj_gemm_kernel<<<dim3(8, 64), 256, 0, stream>>>(ob, wprojt, bproj, out);
}